// Round 3
// baseline (2148.508 us; speedup 1.0000x reference)
//
#include <hip/hip_runtime.h>
#include <hip/hip_bf16.h>

#define DI __device__ __forceinline__

typedef unsigned short u16;
typedef unsigned int   u32;
typedef float  f32x4  __attribute__((ext_vector_type(4)));
typedef __bf16 bf16x8 __attribute__((ext_vector_type(8)));
typedef u16    us8    __attribute__((ext_vector_type(8)));

DI u16 f2bf(float f){
  u32 u = __builtin_bit_cast(u32, f);
  u = (u + 0x7fffu + ((u >> 16) & 1u)) >> 16;
  return (u16)u;
}
DI float bf2f(u16 h){
  u32 u = ((u32)h) << 16;
  return __builtin_bit_cast(float, u);
}

DI f32x4 mfma16(bf16x8 a, bf16x8 b, f32x4 c){
  return __builtin_amdgcn_mfma_f32_16x16x32_bf16(a, b, c, 0, 0, 0);
}
DI bf16x8 ld8s(const u16* p){ return *(const bf16x8*)p; }

DI int winlab(int t, int wh, int ww){
  const int r = t / 7, c = t - r*7;
  const int rh = (wh == 15) ? ((r < 4) ? 1 : 2) : 0;
  const int rw = (ww == 15) ? ((c < 4) ? 1 : 2) : 0;
  return rh*3 + rw;
}

// ---------------------------------------------------------------------------
// Kernel 0: weight prep — bf16 transposed copies (+ lo parts for MLP weights)
//           + rel-pos bias table
// ---------------------------------------------------------------------------
__global__ void prep_kernel(const float* __restrict__ qkv_w, const float* __restrict__ proj_w,
                            const float* __restrict__ w1,    const float* __restrict__ w2,
                            const float* __restrict__ rpb,
                            u16* __restrict__ qkvwT, u16* __restrict__ projwT,
                            u16* __restrict__ w1T,   u16* __restrict__ w2T,
                            u16* __restrict__ w1Tl,  u16* __restrict__ w2Tl,
                            float* __restrict__ biasT)
{
  const int idx = blockIdx.x * blockDim.x + threadIdx.x;
  const int stride = gridDim.x * blockDim.x;
  for (int i = idx; i < 384*128; i += stride){ int o = i >> 7, k = i & 127; qkvwT[i] = f2bf(qkv_w[k*384 + o]); }
  for (int i = idx; i < 128*128; i += stride){ int o = i >> 7, k = i & 127; projwT[i] = f2bf(proj_w[k*128 + o]); }
  for (int i = idx; i < 512*128; i += stride){
    int o = i >> 7, k = i & 127;
    float w = w1[k*512 + o];
    u16 h = f2bf(w);
    w1T[i]  = h;
    w1Tl[i] = f2bf(w - bf2f(h));
  }
  for (int i = idx; i < 128*512; i += stride){
    int o = i >> 9, k = i & 511;
    float w = w2[k*128 + o];
    u16 h = f2bf(w);
    w2T[i]  = h;
    w2Tl[i] = f2bf(w - bf2f(h));
  }
  for (int i = idx; i < 8*49*49; i += stride){
    int h = i / 2401, rem = i % 2401, ti = rem / 49, tj = rem % 49;
    int ri = ti / 7, ci = ti % 7, rj = tj / 7, cj = tj % 7;
    int rel = (ri - rj + 6) * 13 + (ci - cj + 6);
    biasT[i] = rpb[rel*8 + h];
  }
}

// ---------------------------------------------------------------------------
// Kernel 1: one block = one 7x7 window. LN1 + shift-gather + QKV(MFMA) +
//           scalar fp32 attention (bisect) + proj(MFMA) + residual write.
// ---------------------------------------------------------------------------
__global__ __launch_bounds__(256, 1) void attn_kernel(
    const float* __restrict__ x,
    const float* __restrict__ ln1w, const float* __restrict__ ln1b,
    const float* __restrict__ qkv_b, const float* __restrict__ proj_b,
    const u16* __restrict__ qkvwT, const u16* __restrict__ projwT,
    const float* __restrict__ biasT,
    float* __restrict__ y)
{
  __shared__ u16 xw[64*128];     // phase A: xn bf16 (swizzled). phase B: ao bf16
  __shared__ float qf[64*128];   // fp32 q (+bias, unscaled)
  __shared__ float kf[64*128];   // fp32 k
  __shared__ float vf[64*128];   // fp32 v
  __shared__ float mu_s[64], rs_s[64];

  const int tid = threadIdx.x;
  const int lane = tid & 63;
  const int wv = tid >> 6;       // wave 0..3
  const int l15 = lane & 15;
  const int lq  = lane >> 4;     // 0..3
  const int blk = blockIdx.x;
  const int b  = blk >> 8;
  const int wi = blk & 255;
  const int wh = wi >> 4, ww = wi & 15;

  // ---- Stage 1: gather (roll -3,-3) + LN1 -> xw (bf16, swizzled), stats ----
  {
    const int t = tid >> 2;     // token 0..63
    const int g = tid & 3;      // channel quarter
    float vals[32];
    float sum = 0.f, sq = 0.f;
    if (t < 49){
      const int r = t / 7, c = t % 7;
      const int hs   = (wh*7 + r + 3) % 112;
      const int wsrc = (ww*7 + c + 3) % 112;
      const float* src = x + ((size_t)((b*112 + hs)*112 + wsrc))*128 + g*32;
      #pragma unroll
      for (int j = 0; j < 8; j++){
        float4 v4 = *(const float4*)(src + 4*j);
        vals[4*j+0]=v4.x; vals[4*j+1]=v4.y; vals[4*j+2]=v4.z; vals[4*j+3]=v4.w;
        sum += v4.x + v4.y + v4.z + v4.w;
        sq  += v4.x*v4.x + v4.y*v4.y + v4.z*v4.z + v4.w*v4.w;
      }
    }
    sum += __shfl_xor(sum, 1); sum += __shfl_xor(sum, 2);
    sq  += __shfl_xor(sq, 1);  sq  += __shfl_xor(sq, 2);
    const float mu = sum * (1.f/128.f);
    const float var = sq * (1.f/128.f) - mu*mu;
    const float rs = rsqrtf(var + 1e-5f);
    if (g == 0){ mu_s[t] = mu; rs_s[t] = rs; }
    #pragma unroll
    for (int j = 0; j < 32; j++){
      const int ch = g*32 + j;
      float xn = 0.f;
      if (t < 49) xn = (vals[j] - mu) * rs * ln1w[ch] + ln1b[ch];
      xw[(t*128 + ch) ^ ((t & 7) << 3)] = f2bf(xn);
    }
  }
  __syncthreads();

  // ---- Stage 2: QKV GEMM [64x128]@[128x384] -> fp32 qf/kf/vf ----
  {
    const f32x4 fz = {0.f,0.f,0.f,0.f};
    f32x4 acc[4][6];
    #pragma unroll
    for (int mt = 0; mt < 4; mt++)
      #pragma unroll
      for (int nt = 0; nt < 6; nt++) acc[mt][nt] = fz;

    const int col0 = wv * 96;
    #pragma unroll
    for (int kk = 0; kk < 4; kk++){
      const int k0 = kk*32 + (lq << 3);
      bf16x8 a[4];
      #pragma unroll
      for (int mt = 0; mt < 4; mt++){
        const int row = mt*16 + l15;
        a[mt] = ld8s(&xw[(row*128 + k0) ^ ((row & 7) << 3)]);
      }
      #pragma unroll
      for (int nt = 0; nt < 6; nt++){
        const int o = col0 + nt*16 + l15;
        const bf16x8 bb = *(const bf16x8*)(qkvwT + o*128 + k0);
        #pragma unroll
        for (int mt = 0; mt < 4; mt++)
          acc[mt][nt] = mfma16(a[mt], bb, acc[mt][nt]);
      }
    }
    // scatter fp32
    #pragma unroll
    for (int nt = 0; nt < 6; nt++){
      const int o = col0 + nt*16 + l15;
      const int which = o >> 7;          // 0:q 1:k 2:v
      const int ch = o & 127;
      const float bias = qkv_b[o];
      #pragma unroll
      for (int mt = 0; mt < 4; mt++){
        #pragma unroll
        for (int r = 0; r < 4; r++){
          const int tok = mt*16 + (lq << 2) + r;
          const float v = acc[mt][nt][r] + bias;
          if (which == 0)      qf[tok*128 + ch] = v;
          else if (which == 1) kf[tok*128 + ch] = v;
          else                 vf[tok*128 + ch] = v;
        }
      }
    }
  }
  __syncthreads();

  // ---- Stage 3 (bisect): scalar fp32 attention, one thread per (row,head) --
  {
    for (int it = tid; it < 49*8; it += 256){
      const int h   = it / 49;
      const int row = it - h*49;
      const int labr = winlab(row, wh, ww);
      float qreg[16];
      #pragma unroll
      for (int d = 0; d < 16; d++) qreg[d] = qf[row*128 + h*16 + d];
      float s[49];
      float mx = -3e38f;
      for (int j = 0; j < 49; j++){
        float acc = 0.f;
        #pragma unroll
        for (int d = 0; d < 16; d++) acc += qreg[d] * kf[j*128 + h*16 + d];
        acc = acc * 0.25f + biasT[h*2401 + row*49 + j];
        if (labr != winlab(j, wh, ww)) acc -= 100.f;
        s[j] = acc;
        mx = fmaxf(mx, acc);
      }
      float sum = 0.f;
      for (int j = 0; j < 49; j++){
        const float e = __expf(s[j] - mx);
        s[j] = e;
        sum += e;
      }
      const float inv = 1.f / sum;
      float o[16];
      #pragma unroll
      for (int d = 0; d < 16; d++) o[d] = 0.f;
      for (int j = 0; j < 49; j++){
        const float p = s[j] * inv;
        #pragma unroll
        for (int d = 0; d < 16; d++) o[d] += p * vf[j*128 + h*16 + d];
      }
      #pragma unroll
      for (int d = 0; d < 16; d++){
        const int ch = h*16 + d;
        xw[(row*128 + ch) ^ ((row & 7) << 3)] = f2bf(o[d]);   // xw reused as ao
      }
    }
  }
  __syncthreads();

  // ---- Stage 4: proj [64x128]@[128x128] + residual (xn recomputed fp32) ----
  {
    const f32x4 fz = {0.f,0.f,0.f,0.f};
    f32x4 acc[4][2];
    #pragma unroll
    for (int mt = 0; mt < 4; mt++){ acc[mt][0] = fz; acc[mt][1] = fz; }
    #pragma unroll
    for (int kk = 0; kk < 4; kk++){
      const int k0 = kk*32 + (lq << 3);
      bf16x8 a[4];
      #pragma unroll
      for (int mt = 0; mt < 4; mt++){
        const int row = mt*16 + l15;
        a[mt] = ld8s(&xw[(row*128 + k0) ^ ((row & 7) << 3)]);
      }
      #pragma unroll
      for (int nt = 0; nt < 2; nt++){
        const int o = wv*32 + nt*16 + l15;
        const bf16x8 bb = *(const bf16x8*)(projwT + o*128 + k0);
        #pragma unroll
        for (int mt = 0; mt < 4; mt++)
          acc[mt][nt] = mfma16(a[mt], bb, acc[mt][nt]);
      }
    }
    #pragma unroll
    for (int nt = 0; nt < 2; nt++){
      const int ch = wv*32 + nt*16 + l15;
      const float pb = proj_b[ch];
      const float lw = ln1w[ch], lb = ln1b[ch];
      #pragma unroll
      for (int mt = 0; mt < 4; mt++){
        #pragma unroll
        for (int r = 0; r < 4; r++){
          const int tok = mt*16 + (lq << 2) + r;
          if (tok < 49){
            const int rr = tok / 7, cc = tok % 7;
            const int hs   = (wh*7 + rr + 3) % 112;
            const int wsrc = (ww*7 + cc + 3) % 112;
            const size_t gi = ((size_t)((b*112 + hs)*112 + wsrc))*128 + ch;
            const float xn = (x[gi] - mu_s[tok]) * rs_s[tok] * lw + lb;
            y[gi] = xn + acc[mt][nt][r] + pb;
          }
        }
      }
    }
  }
}

// ---------------------------------------------------------------------------
// Kernel 2: MLP over 64-token tiles, in-place on y (= d_out).
// Hi/lo bf16-split GEMMs (3 MFMA terms) -> near-fp32 precision.
// ---------------------------------------------------------------------------
__global__ __launch_bounds__(256) void mlp_kernel(
    const float* __restrict__ ln2w, const float* __restrict__ ln2b,
    const float* __restrict__ b1, const float* __restrict__ b2,
    const u16* __restrict__ w1T, const u16* __restrict__ w1Tl,
    const u16* __restrict__ w2T, const u16* __restrict__ w2Tl,
    float* __restrict__ y)
{
  __shared__ u16 ynh[64*128];    // 16KB  yn hi
  __shared__ u16 ynl[64*128];    // 16KB  yn lo
  __shared__ u16 hidh[64*256];   // 32KB  hid hi (one 256-col half)
  __shared__ u16 hidl[64*256];   // 32KB  hid lo
  const int tid = threadIdx.x;
  const int lane = tid & 63;
  const int wv = tid >> 6;
  const int l15 = lane & 15;
  const int lq  = lane >> 4;
  const size_t base = (size_t)blockIdx.x * 64;
  const f32x4 fz = {0.f,0.f,0.f,0.f};

  // LN2 -> yn hi/lo
  {
    const int t = tid >> 2, g = tid & 3;
    const float* src = y + (base + t)*128 + g*32;
    float vals[32];
    float sum = 0.f, sq = 0.f;
    #pragma unroll
    for (int j = 0; j < 8; j++){
      float4 v4 = *(const float4*)(src + 4*j);
      vals[4*j+0]=v4.x; vals[4*j+1]=v4.y; vals[4*j+2]=v4.z; vals[4*j+3]=v4.w;
      sum += v4.x + v4.y + v4.z + v4.w;
      sq  += v4.x*v4.x + v4.y*v4.y + v4.z*v4.z + v4.w*v4.w;
    }
    sum += __shfl_xor(sum, 1); sum += __shfl_xor(sum, 2);
    sq  += __shfl_xor(sq, 1);  sq  += __shfl_xor(sq, 2);
    const float mu = sum * (1.f/128.f);
    const float rs = rsqrtf(sq * (1.f/128.f) - mu*mu + 1e-5f);
    #pragma unroll
    for (int j = 0; j < 32; j++){
      const int ch = g*32 + j;
      const float v = (vals[j] - mu) * rs * ln2w[ch] + ln2b[ch];
      const u16 h = f2bf(v);
      const int idx = (t*128 + ch) ^ ((t & 7) << 3);
      ynh[idx] = h;
      ynl[idx] = f2bf(v - bf2f(h));
    }
  }
  __syncthreads();

  f32x4 acc2[4][2];
  #pragma unroll
  for (int mt = 0; mt < 4; mt++){ acc2[mt][0] = fz; acc2[mt][1] = fz; }

  #pragma unroll 1
  for (int half = 0; half < 2; half++){
    // GEMM1 [64x128]@[128x256] + GELU -> hid (hi/lo), 3-term split
    {
      f32x4 acc[4][4];
      #pragma unroll
      for (int mt = 0; mt < 4; mt++)
        #pragma unroll
        for (int nt = 0; nt < 4; nt++) acc[mt][nt] = fz;
      #pragma unroll
      for (int kk = 0; kk < 4; kk++){
        const int k0 = kk*32 + (lq << 3);
        bf16x8 ah[4], al[4];
        #pragma unroll
        for (int mt = 0; mt < 4; mt++){
          const int row = mt*16 + l15;
          const int idx = (row*128 + k0) ^ ((row & 7) << 3);
          ah[mt] = ld8s(&ynh[idx]);
          al[mt] = ld8s(&ynl[idx]);
        }
        #pragma unroll
        for (int nt = 0; nt < 4; nt++){
          const int o = half*256 + wv*64 + nt*16 + l15;
          const bf16x8 bh = *(const bf16x8*)(w1T  + o*128 + k0);
          const bf16x8 bl = *(const bf16x8*)(w1Tl + o*128 + k0);
          #pragma unroll
          for (int mt = 0; mt < 4; mt++){
            acc[mt][nt] = mfma16(ah[mt], bh, acc[mt][nt]);
            acc[mt][nt] = mfma16(al[mt], bh, acc[mt][nt]);
            acc[mt][nt] = mfma16(ah[mt], bl, acc[mt][nt]);
          }
        }
      }
      #pragma unroll
      for (int nt = 0; nt < 4; nt++){
        const int o = half*256 + wv*64 + nt*16 + l15;
        const int cl = o - half*256;           // local col 0..255
        const float bb1 = b1[o];
        #pragma unroll
        for (int mt = 0; mt < 4; mt++){
          #pragma unroll
          for (int r = 0; r < 4; r++){
            const int tok = mt*16 + (lq << 2) + r;
            const float v = acc[mt][nt][r] + bb1;
            const float u = 0.7978845608028654f * (v + 0.044715f * v*v*v);
            const float th = 1.f - 2.f / (__expf(2.f*u) + 1.f);
            const float gel = 0.5f * v * (1.f + th);
            const u16 gh = f2bf(gel);
            const int idx = (tok*256 + cl) ^ ((tok & 7) << 3);
            hidh[idx] = gh;
            hidl[idx] = f2bf(gel - bf2f(gh));
          }
        }
      }
    }
    __syncthreads();

    // GEMM2 partial: [64x256]@[256x128], 3-term split, accumulate acc2
    {
      #pragma unroll
      for (int kk = 0; kk < 8; kk++){
        const int k0 = kk*32 + (lq << 3);      // local k in half: 0..255
        bf16x8 ah[4], al[4];
        #pragma unroll
        for (int mt = 0; mt < 4; mt++){
          const int row = mt*16 + l15;
          const int idx = (row*256 + k0) ^ ((row & 7) << 3);
          ah[mt] = ld8s(&hidh[idx]);
          al[mt] = ld8s(&hidl[idx]);
        }
        #pragma unroll
        for (int nt = 0; nt < 2; nt++){
          const int o = wv*32 + nt*16 + l15;
          const int kg = half*256 + k0;
          const bf16x8 bh = *(const bf16x8*)(w2T  + o*512 + kg);
          const bf16x8 bl = *(const bf16x8*)(w2Tl + o*512 + kg);
          #pragma unroll
          for (int mt = 0; mt < 4; mt++){
            acc2[mt][nt] = mfma16(ah[mt], bh, acc2[mt][nt]);
            acc2[mt][nt] = mfma16(al[mt], bh, acc2[mt][nt]);
            acc2[mt][nt] = mfma16(ah[mt], bl, acc2[mt][nt]);
          }
        }
      }
    }
    __syncthreads();
  }

  // epilogue: out = y + hid, in place
  #pragma unroll
  for (int nt = 0; nt < 2; nt++){
    const int ch = wv*32 + nt*16 + l15;
    const float bb2 = b2[ch];
    #pragma unroll
    for (int mt = 0; mt < 4; mt++){
      #pragma unroll
      for (int r = 0; r < 4; r++){
        const int tok = mt*16 + (lq << 2) + r;
        const size_t gi = (base + tok)*128 + ch;
        y[gi] = y[gi] + acc2[mt][nt][r] + bb2;
      }
    }
  }
}

// ---------------------------------------------------------------------------
extern "C" void kernel_launch(void* const* d_in, const int* in_sizes, int n_in,
                              void* d_out, int out_size, void* d_ws, size_t ws_size,
                              hipStream_t stream)
{
  const float* x      = (const float*)d_in[0];
  const float* qkv_w  = (const float*)d_in[1];
  const float* qkv_b  = (const float*)d_in[2];
  const float* proj_w = (const float*)d_in[3];
  const float* proj_b = (const float*)d_in[4];
  const float* rpb    = (const float*)d_in[5];
  const float* ln1w   = (const float*)d_in[6];
  const float* ln1b   = (const float*)d_in[7];
  const float* ln2w   = (const float*)d_in[8];
  const float* ln2b   = (const float*)d_in[9];
  const float* w1     = (const float*)d_in[10];
  const float* b1     = (const float*)d_in[11];
  const float* w2     = (const float*)d_in[12];
  const float* b2     = (const float*)d_in[13];

  char* ws = (char*)d_ws;
  u16*   qkvwT  = (u16*)(ws + 0);        // 384*128*2  = 98304
  u16*   projwT = (u16*)(ws + 98304);    // 128*128*2  = 32768   -> 131072
  u16*   w1T    = (u16*)(ws + 131072);   // 512*128*2  = 131072  -> 262144
  u16*   w2T    = (u16*)(ws + 262144);   // 128*512*2  = 131072  -> 393216
  float* biasT  = (float*)(ws + 393216); // 8*49*49*4  = 307328  -> 700544
  u16*   w1Tl   = (u16*)(ws + 700544);   // 131072 -> 831616
  u16*   w2Tl   = (u16*)(ws + 831616);   // 131072 -> 962688
  float* y = (float*)d_out;

  prep_kernel<<<512, 256, 0, stream>>>(qkv_w, proj_w, w1, w2, rpb,
                                       qkvwT, projwT, w1T, w2T, w1Tl, w2Tl, biasT);
  attn_kernel<<<8192, 256, 0, stream>>>(x, ln1w, ln1b, qkv_b, proj_b,
                                        qkvwT, projwT, biasT, y);
  mlp_kernel<<<6272, 256, 0, stream>>>(ln2w, ln2b, b1, b2,
                                       w1T, w1Tl, w2T, w2Tl, y);
}

// Round 4
// 1625.791 us; speedup vs baseline: 1.3215x; 1.3215x over previous
//
#include <hip/hip_runtime.h>
#include <hip/hip_bf16.h>

#define DI __device__ __forceinline__

typedef unsigned short u16;
typedef unsigned int   u32;
typedef float  f32x4  __attribute__((ext_vector_type(4)));
typedef __bf16 bf16x8 __attribute__((ext_vector_type(8)));
typedef u16    us8    __attribute__((ext_vector_type(8)));

DI u16 f2bf(float f){
  u32 u = __builtin_bit_cast(u32, f);
  u = (u + 0x7fffu + ((u >> 16) & 1u)) >> 16;
  return (u16)u;
}
DI float bf2f(u16 h){
  u32 u = ((u32)h) << 16;
  return __builtin_bit_cast(float, u);
}

DI f32x4 mfma16(bf16x8 a, bf16x8 b, f32x4 c){
  return __builtin_amdgcn_mfma_f32_16x16x32_bf16(a, b, c, 0, 0, 0);
}
DI bf16x8 bzero(){
  us8 z = {0,0,0,0,0,0,0,0};
  return __builtin_bit_cast(bf16x8, z);
}
DI bf16x8 ld8s(const u16* p){ return *(const bf16x8*)p; }

// ---------------------------------------------------------------------------
// Kernel 0: weight prep — bf16 transposed copies (+ lo parts for MLP weights)
//           + rel-pos bias table TRANSPOSED: biasT[h][key][query]
// ---------------------------------------------------------------------------
__global__ void prep_kernel(const float* __restrict__ qkv_w, const float* __restrict__ proj_w,
                            const float* __restrict__ w1,    const float* __restrict__ w2,
                            const float* __restrict__ rpb,
                            u16* __restrict__ qkvwT, u16* __restrict__ projwT,
                            u16* __restrict__ w1T,   u16* __restrict__ w2T,
                            u16* __restrict__ w1Tl,  u16* __restrict__ w2Tl,
                            float* __restrict__ biasT)
{
  const int idx = blockIdx.x * blockDim.x + threadIdx.x;
  const int stride = gridDim.x * blockDim.x;
  for (int i = idx; i < 384*128; i += stride){ int o = i >> 7, k = i & 127; qkvwT[i] = f2bf(qkv_w[k*384 + o]); }
  for (int i = idx; i < 128*128; i += stride){ int o = i >> 7, k = i & 127; projwT[i] = f2bf(proj_w[k*128 + o]); }
  for (int i = idx; i < 512*128; i += stride){
    int o = i >> 7, k = i & 127;
    float w = w1[k*512 + o];
    u16 h = f2bf(w);
    w1T[i]  = h;
    w1Tl[i] = f2bf(w - bf2f(h));
  }
  for (int i = idx; i < 128*512; i += stride){
    int o = i >> 9, k = i & 511;
    float w = w2[k*128 + o];
    u16 h = f2bf(w);
    w2T[i]  = h;
    w2Tl[i] = f2bf(w - bf2f(h));
  }
  // biasT[h*2401 + key*49 + query] = rpb[REL_IDX[query][key]*8 + h]
  for (int i = idx; i < 8*49*49; i += stride){
    int h = i / 2401, rem = i % 2401, a = rem / 49, b = rem % 49; // a=key, b=query
    int rel = (b/7 - a/7 + 6) * 13 + (b%7 - a%7 + 6);
    biasT[i] = rpb[rel*8 + h];
  }
}

// ---------------------------------------------------------------------------
// Kernel 1: one block = one 7x7 window. LN1 + shift-gather + QKV(MFMA) +
//           MFMA attention (S^T trick, P in registers) + proj + residual.
// ---------------------------------------------------------------------------
__global__ __launch_bounds__(256, 2) void attn_kernel(
    const float* __restrict__ x,
    const float* __restrict__ ln1w, const float* __restrict__ ln1b,
    const float* __restrict__ qkv_b, const float* __restrict__ proj_b,
    const u16* __restrict__ qkvwT, const u16* __restrict__ projwT,
    const float* __restrict__ biasT,
    float* __restrict__ y)
{
  __shared__ u16 xw[64*128];     // phase A: xn bf16 (swizzled). phase B: ao bf16
  __shared__ u16 qB[64*136];     // q*scale bf16 [tok][ch], padded stride 136
  __shared__ u16 kB[64*136];     // k bf16 [tok][ch], padded stride 136
  __shared__ u16 vTl[128*72];    // v bf16 transposed [ch][tok], padded stride 72
  __shared__ float mu_s[64], rs_s[64];
  __shared__ int lab_s[64];

  const int tid = threadIdx.x;
  const int lane = tid & 63;
  const int wv = tid >> 6;       // wave 0..3
  const int l15 = lane & 15;
  const int lq  = lane >> 4;     // 0..3
  const int blk = blockIdx.x;
  const int b  = blk >> 8;
  const int wi = blk & 255;
  const int wh = wi >> 4, ww = wi & 15;

  // ---- Stage 1: gather (roll -3,-3) + LN1 -> xw (bf16, swizzled), stats ----
  {
    const int t = tid >> 2;     // token 0..63
    const int g = tid & 3;      // channel quarter
    float vals[32];
    float sum = 0.f, sq = 0.f;
    if (t < 49){
      const int r = t / 7, c = t % 7;
      const int hs   = (wh*7 + r + 3) % 112;
      const int wsrc = (ww*7 + c + 3) % 112;
      const float* src = x + ((size_t)((b*112 + hs)*112 + wsrc))*128 + g*32;
      #pragma unroll
      for (int j = 0; j < 8; j++){
        float4 v4 = *(const float4*)(src + 4*j);
        vals[4*j+0]=v4.x; vals[4*j+1]=v4.y; vals[4*j+2]=v4.z; vals[4*j+3]=v4.w;
        sum += v4.x + v4.y + v4.z + v4.w;
        sq  += v4.x*v4.x + v4.y*v4.y + v4.z*v4.z + v4.w*v4.w;
      }
    }
    sum += __shfl_xor(sum, 1); sum += __shfl_xor(sum, 2);
    sq  += __shfl_xor(sq, 1);  sq  += __shfl_xor(sq, 2);
    const float mu = sum * (1.f/128.f);
    const float var = sq * (1.f/128.f) - mu*mu;
    const float rs = rsqrtf(var + 1e-5f);
    if (g == 0){
      mu_s[t] = mu; rs_s[t] = rs;
      const int r = t / 7, c = t % 7;
      const int rh = (wh == 15) ? ((r < 4) ? 1 : 2) : 0;
      const int rw = (ww == 15) ? ((c < 4) ? 1 : 2) : 0;
      lab_s[t] = rh*3 + rw;
    }
    #pragma unroll
    for (int j = 0; j < 32; j++){
      const int ch = g*32 + j;
      float xn = 0.f;
      if (t < 49) xn = (vals[j] - mu) * rs * ln1w[ch] + ln1b[ch];
      xw[(t*128 + ch) ^ ((t & 7) << 3)] = f2bf(xn);
    }
  }
  __syncthreads();

  // ---- Stage 2: QKV GEMM [64x128]@[128x384] -> qB/kB/vTl (bf16, padded) ----
  {
    const f32x4 fz = {0.f,0.f,0.f,0.f};
    f32x4 acc[4][6];
    #pragma unroll
    for (int mt = 0; mt < 4; mt++)
      #pragma unroll
      for (int nt = 0; nt < 6; nt++) acc[mt][nt] = fz;

    const int col0 = wv * 96;
    #pragma unroll
    for (int kk = 0; kk < 4; kk++){
      const int k0 = kk*32 + (lq << 3);
      bf16x8 a[4];
      #pragma unroll
      for (int mt = 0; mt < 4; mt++){
        const int row = mt*16 + l15;
        a[mt] = ld8s(&xw[(row*128 + k0) ^ ((row & 7) << 3)]);
      }
      #pragma unroll
      for (int nt = 0; nt < 6; nt++){
        const int o = col0 + nt*16 + l15;
        const bf16x8 bb = *(const bf16x8*)(qkvwT + o*128 + k0);
        #pragma unroll
        for (int mt = 0; mt < 4; mt++)
          acc[mt][nt] = mfma16(a[mt], bb, acc[mt][nt]);
      }
    }
    #pragma unroll
    for (int nt = 0; nt < 6; nt++){
      const int o = col0 + nt*16 + l15;
      const int which = o >> 7;          // 0:q 1:k 2:v
      const int ch = o & 127;
      const float bias = qkv_b[o];
      #pragma unroll
      for (int mt = 0; mt < 4; mt++){
        #pragma unroll
        for (int r = 0; r < 4; r++){
          const int tok = mt*16 + (lq << 2) + r;
          const float v = acc[mt][nt][r] + bias;
          if (which == 0)      qB[tok*136 + ch] = f2bf(v * 0.25f);
          else if (which == 1) kB[tok*136 + ch] = f2bf(v);
          else                 vTl[ch*72 + tok] = f2bf(v);
        }
      }
    }
  }
  __syncthreads();

  // ---- Stage 3: MFMA attention. S^T = mfma(K, Q); softmax across lq lanes;
  //      P repacked to PV A-frags via shfl (no LDS for P). ----
  {
    const f32x4 fz = {0.f,0.f,0.f,0.f};
    const int iq = wv*16 + l15;            // this lane's query token
    const int labq = lab_s[iq];
    float mterm[4][4];
    #pragma unroll
    for (int nt = 0; nt < 4; nt++)
      #pragma unroll
      for (int r = 0; r < 4; r++){
        const int jk = nt*16 + (lq << 2) + r;   // key token
        float mv = 0.f;
        if (jk >= 49) mv = -1e30f;
        else if (iq < 49 && labq != lab_s[jk]) mv = -100.f;
        mterm[nt][r] = mv;
      }
    #pragma unroll 1
    for (int h = 0; h < 8; h++){
      // B-frag: Q[query=l15(+wv*16)][hd=lq*8+j], hd 16..31 zero-padded
      const bf16x8 bq = (lq < 2) ? ld8s(&qB[iq*136 + h*16 + (lq << 3)]) : bzero();
      float p[4][4];
      #pragma unroll
      for (int nt = 0; nt < 4; nt++){
        // A-frag: K[key=nt*16+l15][hd=lq*8+j]
        const bf16x8 ak = (lq < 2) ? ld8s(&kB[(nt*16 + l15)*136 + h*16 + (lq << 3)]) : bzero();
        const f32x4 s4 = mfma16(ak, bq, fz);   // D[key][query]
        #pragma unroll
        for (int r = 0; r < 4; r++){
          const int jk = nt*16 + (lq << 2) + r;
          float s = s4[r] + mterm[nt][r];
          if (jk < 49 && iq < 49) s += biasT[h*2401 + jk*49 + iq];
          p[nt][r] = s;
        }
      }
      // softmax over keys (regs x lq-lanes) for query iq
      float m = -3e38f;
      #pragma unroll
      for (int nt = 0; nt < 4; nt++)
        #pragma unroll
        for (int r = 0; r < 4; r++) m = fmaxf(m, p[nt][r]);
      m = fmaxf(m, __shfl_xor(m, 16));
      m = fmaxf(m, __shfl_xor(m, 32));
      float sum = 0.f;
      #pragma unroll
      for (int nt = 0; nt < 4; nt++)
        #pragma unroll
        for (int r = 0; r < 4; r++){
          const float e = __expf(p[nt][r] - m);
          p[nt][r] = e;
          sum += e;
        }
      sum += __shfl_xor(sum, 16);
      sum += __shfl_xor(sum, 32);
      const float inv = 1.f / sum;
      #pragma unroll
      for (int nt = 0; nt < 4; nt++)
        #pragma unroll
        for (int r = 0; r < 4; r++) p[nt][r] *= inv;

      // repack: PA A-frag slot (kk, j) = P[query=l15][key=kk*32+lq*8+j]
      bf16x8 pa[2];
      #pragma unroll
      for (int kk = 0; kk < 2; kk++){
        us8 tmp;
        #pragma unroll
        for (int j = 0; j < 8; j++){
          const int srcLane = ((((lq << 1) + (j >> 2)) & 3) << 4) + l15;
          const float va = __shfl(p[2*kk    ][j & 3], srcLane);
          const float vb = __shfl(p[2*kk + 1][j & 3], srcLane);
          tmp[j] = f2bf((lq & 2) ? vb : va);
        }
        pa[kk] = __builtin_bit_cast(bf16x8, tmp);
      }
      // PV: O[query][d] ; B-frag = V[key=kk*32+lq*8+j][d=l15]
      f32x4 oacc = fz;
      #pragma unroll
      for (int kk = 0; kk < 2; kk++){
        const bf16x8 bv = ld8s(&vTl[(h*16 + l15)*72 + kk*32 + (lq << 3)]);
        oacc = mfma16(pa[kk], bv, oacc);
      }
      #pragma unroll
      for (int r = 0; r < 4; r++){
        const int tok = wv*16 + (lq << 2) + r;
        const int ch = h*16 + l15;
        xw[(tok*128 + ch) ^ ((tok & 7) << 3)] = f2bf(oacc[r]);   // xw reused as ao
      }
    }
  }
  __syncthreads();

  // ---- Stage 4: proj [64x128]@[128x128] + residual (xn recomputed fp32) ----
  {
    const f32x4 fz = {0.f,0.f,0.f,0.f};
    f32x4 acc[4][2];
    #pragma unroll
    for (int mt = 0; mt < 4; mt++){ acc[mt][0] = fz; acc[mt][1] = fz; }
    #pragma unroll
    for (int kk = 0; kk < 4; kk++){
      const int k0 = kk*32 + (lq << 3);
      bf16x8 a[4];
      #pragma unroll
      for (int mt = 0; mt < 4; mt++){
        const int row = mt*16 + l15;
        a[mt] = ld8s(&xw[(row*128 + k0) ^ ((row & 7) << 3)]);
      }
      #pragma unroll
      for (int nt = 0; nt < 2; nt++){
        const int o = wv*32 + nt*16 + l15;
        const bf16x8 bb = *(const bf16x8*)(projwT + o*128 + k0);
        #pragma unroll
        for (int mt = 0; mt < 4; mt++)
          acc[mt][nt] = mfma16(a[mt], bb, acc[mt][nt]);
      }
    }
    #pragma unroll
    for (int nt = 0; nt < 2; nt++){
      const int ch = wv*32 + nt*16 + l15;
      const float pb = proj_b[ch];
      const float lw = ln1w[ch], lb = ln1b[ch];
      #pragma unroll
      for (int mt = 0; mt < 4; mt++){
        #pragma unroll
        for (int r = 0; r < 4; r++){
          const int tok = mt*16 + (lq << 2) + r;
          if (tok < 49){
            const int rr = tok / 7, cc = tok % 7;
            const int hs   = (wh*7 + rr + 3) % 112;
            const int wsrc = (ww*7 + cc + 3) % 112;
            const size_t gi = ((size_t)((b*112 + hs)*112 + wsrc))*128 + ch;
            const float xn = (x[gi] - mu_s[tok]) * rs_s[tok] * lw + lb;
            y[gi] = xn + acc[mt][nt][r] + pb;
          }
        }
      }
    }
  }
}

// ---------------------------------------------------------------------------
// Kernel 2: MLP over 64-token tiles, in-place on y (= d_out).
// Hi/lo bf16-split GEMMs (3 MFMA terms) -> near-fp32 precision. (unchanged)
// ---------------------------------------------------------------------------
__global__ __launch_bounds__(256) void mlp_kernel(
    const float* __restrict__ ln2w, const float* __restrict__ ln2b,
    const float* __restrict__ b1, const float* __restrict__ b2,
    const u16* __restrict__ w1T, const u16* __restrict__ w1Tl,
    const u16* __restrict__ w2T, const u16* __restrict__ w2Tl,
    float* __restrict__ y)
{
  __shared__ u16 ynh[64*128];
  __shared__ u16 ynl[64*128];
  __shared__ u16 hidh[64*256];
  __shared__ u16 hidl[64*256];
  const int tid = threadIdx.x;
  const int lane = tid & 63;
  const int wv = tid >> 6;
  const int l15 = lane & 15;
  const int lq  = lane >> 4;
  const size_t base = (size_t)blockIdx.x * 64;
  const f32x4 fz = {0.f,0.f,0.f,0.f};

  // LN2 -> yn hi/lo
  {
    const int t = tid >> 2, g = tid & 3;
    const float* src = y + (base + t)*128 + g*32;
    float vals[32];
    float sum = 0.f, sq = 0.f;
    #pragma unroll
    for (int j = 0; j < 8; j++){
      float4 v4 = *(const float4*)(src + 4*j);
      vals[4*j+0]=v4.x; vals[4*j+1]=v4.y; vals[4*j+2]=v4.z; vals[4*j+3]=v4.w;
      sum += v4.x + v4.y + v4.z + v4.w;
      sq  += v4.x*v4.x + v4.y*v4.y + v4.z*v4.z + v4.w*v4.w;
    }
    sum += __shfl_xor(sum, 1); sum += __shfl_xor(sum, 2);
    sq  += __shfl_xor(sq, 1);  sq  += __shfl_xor(sq, 2);
    const float mu = sum * (1.f/128.f);
    const float rs = rsqrtf(sq * (1.f/128.f) - mu*mu + 1e-5f);
    #pragma unroll
    for (int j = 0; j < 32; j++){
      const int ch = g*32 + j;
      const float v = (vals[j] - mu) * rs * ln2w[ch] + ln2b[ch];
      const u16 h = f2bf(v);
      const int idx = (t*128 + ch) ^ ((t & 7) << 3);
      ynh[idx] = h;
      ynl[idx] = f2bf(v - bf2f(h));
    }
  }
  __syncthreads();

  f32x4 acc2[4][2];
  #pragma unroll
  for (int mt = 0; mt < 4; mt++){ acc2[mt][0] = fz; acc2[mt][1] = fz; }

  #pragma unroll 1
  for (int half = 0; half < 2; half++){
    {
      f32x4 acc[4][4];
      #pragma unroll
      for (int mt = 0; mt < 4; mt++)
        #pragma unroll
        for (int nt = 0; nt < 4; nt++) acc[mt][nt] = fz;
      #pragma unroll
      for (int kk = 0; kk < 4; kk++){
        const int k0 = kk*32 + (lq << 3);
        bf16x8 ah[4], al[4];
        #pragma unroll
        for (int mt = 0; mt < 4; mt++){
          const int row = mt*16 + l15;
          const int idx = (row*128 + k0) ^ ((row & 7) << 3);
          ah[mt] = ld8s(&ynh[idx]);
          al[mt] = ld8s(&ynl[idx]);
        }
        #pragma unroll
        for (int nt = 0; nt < 4; nt++){
          const int o = half*256 + wv*64 + nt*16 + l15;
          const bf16x8 bh = *(const bf16x8*)(w1T  + o*128 + k0);
          const bf16x8 bl = *(const bf16x8*)(w1Tl + o*128 + k0);
          #pragma unroll
          for (int mt = 0; mt < 4; mt++){
            acc[mt][nt] = mfma16(ah[mt], bh, acc[mt][nt]);
            acc[mt][nt] = mfma16(al[mt], bh, acc[mt][nt]);
            acc[mt][nt] = mfma16(ah[mt], bl, acc[mt][nt]);
          }
        }
      }
      #pragma unroll
      for (int nt = 0; nt < 4; nt++){
        const int o = half*256 + wv*64 + nt*16 + l15;
        const int cl = o - half*256;
        const float bb1 = b1[o];
        #pragma unroll
        for (int mt = 0; mt < 4; mt++){
          #pragma unroll
          for (int r = 0; r < 4; r++){
            const int tok = mt*16 + (lq << 2) + r;
            const float v = acc[mt][nt][r] + bb1;
            const float u = 0.7978845608028654f * (v + 0.044715f * v*v*v);
            const float th = 1.f - 2.f / (__expf(2.f*u) + 1.f);
            const float gel = 0.5f * v * (1.f + th);
            const u16 gh = f2bf(gel);
            const int idx = (tok*256 + cl) ^ ((tok & 7) << 3);
            hidh[idx] = gh;
            hidl[idx] = f2bf(gel - bf2f(gh));
          }
        }
      }
    }
    __syncthreads();

    {
      #pragma unroll
      for (int kk = 0; kk < 8; kk++){
        const int k0 = kk*32 + (lq << 3);
        bf16x8 ah[4], al[4];
        #pragma unroll
        for (int mt = 0; mt < 4; mt++){
          const int row = mt*16 + l15;
          const int idx = (row*256 + k0) ^ ((row & 7) << 3);
          ah[mt] = ld8s(&hidh[idx]);
          al[mt] = ld8s(&hidl[idx]);
        }
        #pragma unroll
        for (int nt = 0; nt < 2; nt++){
          const int o = wv*32 + nt*16 + l15;
          const int kg = half*256 + k0;
          const bf16x8 bh = *(const bf16x8*)(w2T  + o*512 + kg);
          const bf16x8 bl = *(const bf16x8*)(w2Tl + o*512 + kg);
          #pragma unroll
          for (int mt = 0; mt < 4; mt++){
            acc2[mt][nt] = mfma16(ah[mt], bh, acc2[mt][nt]);
            acc2[mt][nt] = mfma16(al[mt], bh, acc2[mt][nt]);
            acc2[mt][nt] = mfma16(ah[mt], bl, acc2[mt][nt]);
          }
        }
      }
    }
    __syncthreads();
  }

  #pragma unroll
  for (int nt = 0; nt < 2; nt++){
    const int ch = wv*32 + nt*16 + l15;
    const float bb2 = b2[ch];
    #pragma unroll
    for (int mt = 0; mt < 4; mt++){
      #pragma unroll
      for (int r = 0; r < 4; r++){
        const int tok = mt*16 + (lq << 2) + r;
        const size_t gi = (base + tok)*128 + ch;
        y[gi] = y[gi] + acc2[mt][nt][r] + bb2;
      }
    }
  }
}

// ---------------------------------------------------------------------------
extern "C" void kernel_launch(void* const* d_in, const int* in_sizes, int n_in,
                              void* d_out, int out_size, void* d_ws, size_t ws_size,
                              hipStream_t stream)
{
  const float* x      = (const float*)d_in[0];
  const float* qkv_w  = (const float*)d_in[1];
  const float* qkv_b  = (const float*)d_in[2];
  const float* proj_w = (const float*)d_in[3];
  const float* proj_b = (const float*)d_in[4];
  const float* rpb    = (const float*)d_in[5];
  const float* ln1w   = (const float*)d_in[6];
  const float* ln1b   = (const float*)d_in[7];
  const float* ln2w   = (const float*)d_in[8];
  const float* ln2b   = (const float*)d_in[9];
  const float* w1     = (const float*)d_in[10];
  const float* b1     = (const float*)d_in[11];
  const float* w2     = (const float*)d_in[12];
  const float* b2     = (const float*)d_in[13];

  char* ws = (char*)d_ws;
  u16*   qkvwT  = (u16*)(ws + 0);        // 384*128*2  = 98304
  u16*   projwT = (u16*)(ws + 98304);    // 128*128*2  = 32768   -> 131072
  u16*   w1T    = (u16*)(ws + 131072);   // 512*128*2  = 131072  -> 262144
  u16*   w2T    = (u16*)(ws + 262144);   // 128*512*2  = 131072  -> 393216
  float* biasT  = (float*)(ws + 393216); // 8*49*49*4  = 307328  -> 700544
  u16*   w1Tl   = (u16*)(ws + 700544);   // 131072 -> 831616
  u16*   w2Tl   = (u16*)(ws + 831616);   // 131072 -> 962688
  float* y = (float*)d_out;

  prep_kernel<<<512, 256, 0, stream>>>(qkv_w, proj_w, w1, w2, rpb,
                                       qkvwT, projwT, w1T, w2T, w1Tl, w2Tl, biasT);
  attn_kernel<<<8192, 256, 0, stream>>>(x, ln1w, ln1b, qkv_b, proj_b,
                                        qkvwT, projwT, biasT, y);
  mlp_kernel<<<6272, 256, 0, stream>>>(ln2w, ln2b, b1, b2,
                                       w1T, w1Tl, w2T, w2Tl, y);
}